// Round 1
// 100.444 us; speedup vs baseline: 1.0287x; 1.0287x over previous
//
#include <hip/hip_runtime.h>
#include <hip/hip_bf16.h>

// Deformable 3D conv: B=2, CIN=COUT=64, D=8,H=32,W=32, K=27, stride=1,pad=1,dil=1
// Round 5 = per-wave-privatized pipeline:
//  - wave owns 16 positions x all 64 COUT (was 16 COUT x 64 positions), so the
//    sampled tile sS is wave-private -> NO barriers in the kl loop (21 -> 6 per block)
//  - float2 accumulation (v_pk_fma_f32 eligible) + 1-inst v_cvt_pk_bf16_f32 pack
//  - coords computed per-wave (48 lanes) instead of t<192 block-wide
//  - out zero-init folded into pre_kernel (memset dispatch removed)
//  - s_setprio(1) around MFMA cluster (waves now phase-diverge -> T5 applies)

#define BB    2
#define CINC  64
#define COUTC 64
#define DDEP  8
#define HGT   32
#define WID   32
#define KK    27
#define KGRP  3
#define KPG   9         // k's per blockIdx.y group
#define KPH   3         // k's per phase (weight-stage batch)
#define PP    8192      // DOUT*HOUT*WOUT
#define TP    64        // output positions per workgroup
#define LDW   72        // padded LDS row stride (bf16 elems)

typedef short s16x8 __attribute__((ext_vector_type(8)));
typedef float f32x4 __attribute__((ext_vector_type(4)));
typedef float f32x2 __attribute__((ext_vector_type(2)));

__device__ __forceinline__ unsigned short f2bf(float f) {
    unsigned u = __builtin_bit_cast(unsigned, f);
    u += 0x7FFFu + ((u >> 16) & 1u);   // RNE
    return (unsigned short)(u >> 16);
}

__device__ __forceinline__ unsigned pack2bf(float lo, float hi) {
    return (unsigned)f2bf(lo) | ((unsigned)f2bf(hi) << 16);
}

// unpack 2 packed bf16 (2 channels) to float2
__device__ __forceinline__ f32x2 up2(unsigned v) {
    f32x2 r;
    r.x = __builtin_bit_cast(float, v << 16);
    r.y = __builtin_bit_cast(float, v & 0xFFFF0000u);
    return r;
}

// Fused pre-kernel:
//  blocks [0,256): transpose+convert x[b][c][s] fp32 -> xt[b][s][c] bf16
//  blocks [256,688): weight (COUT,CIN,27) fp32 -> wt[(k*64+o)*64+c] bf16
//  blocks [688,1712): zero-init out (replaces hipMemsetAsync dispatch)
#define WBLOCKS 432   // KK*COUTC*CINC / 256
#define ZBLOCKS 1024  // BB*COUTC*PP / 4 / 256
__global__ void pre_kernel(const float* __restrict__ x, const float* __restrict__ w,
                           unsigned short* __restrict__ xt, unsigned short* __restrict__ wt,
                           float* __restrict__ out) {
    __shared__ float sT[64][65];
    const int t    = threadIdx.x;
    const int lane = t & 63;
    const int wv   = t >> 6;
    const int half = lane >> 5;
    const int c2   = lane & 31;
    int blk = blockIdx.x;
    if (blk < 256) {
        int b  = blk >> 7;
        int s0 = (blk & 127) * 64;
        #pragma unroll
        for (int i = 0; i < 16; ++i) {
            int c = wv * 16 + i;
            sT[c][lane] = x[(size_t)(b * CINC + c) * PP + s0 + lane];
        }
        __syncthreads();
        #pragma unroll
        for (int i = 0; i < 8; ++i) {
            int s = wv * 16 + 2 * i + half;
            unsigned pk = pack2bf(sT[2 * c2][s], sT[2 * c2 + 1][s]);
            *(unsigned*)&xt[(size_t)(b * PP + s0 + s) * 64 + 2 * c2] = pk;
        }
    } else if (blk < 256 + WBLOCKS) {
        int id = (blk - 256) * 256 + t;
        if (id < KK * COUTC * CINC) {
            int c = id & 63;
            int o = (id >> 6) & 63;
            int k = id >> 12;
            wt[id] = f2bf(w[(o * CINC + c) * KK + k]);
        }
    } else {
        int id = (blk - 256 - WBLOCKS) * 256 + t;   // float4 index
        ((float4*)out)[id] = make_float4(0.f, 0.f, 0.f, 0.f);
    }
}

__global__ __launch_bounds__(256, 3) void deform_kernel(
    const unsigned short* __restrict__ xt, const float* __restrict__ off,
    const unsigned short* __restrict__ wt, const float* __restrict__ bias,
    float* __restrict__ out)
{
    __shared__ unsigned short sW[KPH * COUTC * LDW] __attribute__((aligned(16))); // 3x [o][c]
    __shared__ unsigned short sS[TP * LDW]          __attribute__((aligned(16))); // [p][c] wave-private slices
    __shared__ int   sIdx[KPH][TP][8] __attribute__((aligned(16)));  // corner short-offsets
    __shared__ float sCf[KPH][TP][8]  __attribute__((aligned(16)));  // corner weights

    const int t    = threadIdx.x;
    const int lane = t & 63;
    const int wv   = t >> 6;
    const int half = lane >> 5;          // position parity within the pair
    const int c2   = lane & 31;          // channel pair index
    const int b    = blockIdx.x >> 7;
    const int p0   = (blockIdx.x & 127) * TP;
    const int kg   = blockIdx.y;

    const unsigned short* xb  = xt + (size_t)b * PP * 64;
    const unsigned short* xbl = xb + 2 * c2;   // per-lane channel base

    f32x4 acc[4];
    #pragma unroll
    for (int g = 0; g < 4; ++g) acc[g] = (f32x4)0.0f;

    const int n0  = lane & 15;
    const int q   = lane >> 4;
    const int cr  = lane & 15;   // coord row within wave slice
    const int ckl = lane >> 4;   // coord kl (0..3, 3 idle)

    #pragma unroll 1
    for (int ph = 0; ph < 3; ++ph) {
        const int kbase = kg * KPG + ph * KPH;

        __syncthreads();   // all waves done reading sW/sIdx of previous phase

        // ---- stage 3 weight tiles (coalesced 16B loads)
        const unsigned short* wk = wt + kbase * (COUTC * CINC);
        #pragma unroll
        for (int j = 0; j < 6; ++j) {
            int idx = j * 2048 + t * 8;
            int kl  = idx >> 12;
            int rem = idx & 4095;
            *(s16x8*)&sW[kl * (COUTC * LDW) + (rem >> 6) * LDW + (rem & 63)] =
                *(const s16x8*)(wk + idx);
        }

        // ---- coords: each wave computes its OWN 16 rows x 3 kl (48 lanes)
        if (ckl < KPH) {
            int k  = kbase + ckl;
            int pl = 16 * wv + cr;
            int pp = p0 + pl;
            int ow = pp & 31;
            int oh = (pp >> 5) & 31;
            int od = pp >> 10;
            int kd = k / 9;
            int kh = (k - kd * 9) / 3;
            int kw = k - kd * 9 - kh * 3;
            const float* ob = off + (size_t)(b * (3 * KK) + 3 * k) * PP + pp;
            float zd = (float)(od - 1 + kd) + ob[0];
            float zh = (float)(oh - 1 + kh) + ob[PP];
            float zw = (float)(ow - 1 + kw) + ob[2 * PP];

            float fdf = floorf(zd); int d0 = (int)fdf; float fd = zd - fdf;
            float fhf = floorf(zh); int h0 = (int)fhf; float fh = zh - fhf;
            float fwf = floorf(zw); int w0 = (int)fwf; float fw = zw - fwf;

            float Bd0 = (d0 >= 0     && d0 < DDEP)     ? 1.0f - fd : 0.0f;
            float Bd1 = (d0 + 1 >= 0 && d0 + 1 < DDEP) ? fd        : 0.0f;
            float Ch0 = (h0 >= 0     && h0 < HGT)      ? 1.0f - fh : 0.0f;
            float Ch1 = (h0 + 1 >= 0 && h0 + 1 < HGT)  ? fh        : 0.0f;
            float Aw0 = (w0 >= 0     && w0 < WID)      ? 1.0f - fw : 0.0f;
            float Aw1 = (w0 + 1 >= 0 && w0 + 1 < WID)  ? fw        : 0.0f;
            int dc0 = min(max(d0, 0), DDEP - 1);
            int dc1 = min(max(d0 + 1, 0), DDEP - 1);
            int hc0 = min(max(h0, 0), HGT - 1);
            int hc1 = min(max(h0 + 1, 0), HGT - 1);
            int wc0 = min(max(w0, 0), WID - 1);
            int wc1 = min(max(w0 + 1, 0), WID - 1);

            int dhb0 = (dc0 * HGT + hc0) * (WID * 64);
            int dhb1 = (dc0 * HGT + hc1) * (WID * 64);
            int dhb2 = (dc1 * HGT + hc0) * (WID * 64);
            int dhb3 = (dc1 * HGT + hc1) * (WID * 64);
            int wo0 = wc0 * 64, wo1 = wc1 * 64;
            sIdx[ckl][pl][0] = dhb0 + wo0;
            sIdx[ckl][pl][1] = dhb1 + wo0;
            sIdx[ckl][pl][2] = dhb2 + wo0;
            sIdx[ckl][pl][3] = dhb3 + wo0;
            sIdx[ckl][pl][4] = dhb0 + wo1;
            sIdx[ckl][pl][5] = dhb1 + wo1;
            sIdx[ckl][pl][6] = dhb2 + wo1;
            sIdx[ckl][pl][7] = dhb3 + wo1;
            float bc0 = Bd0 * Ch0, bc1 = Bd0 * Ch1, bc2 = Bd1 * Ch0, bc3 = Bd1 * Ch1;
            sCf[ckl][pl][0] = bc0 * Aw0;
            sCf[ckl][pl][1] = bc1 * Aw0;
            sCf[ckl][pl][2] = bc2 * Aw0;
            sCf[ckl][pl][3] = bc3 * Aw0;
            sCf[ckl][pl][4] = bc0 * Aw1;
            sCf[ckl][pl][5] = bc1 * Aw1;
            sCf[ckl][pl][6] = bc2 * Aw1;
            sCf[ckl][pl][7] = bc3 * Aw1;
        }
        __syncthreads();   // sW (and coords) visible

        // ---- barrier-free kl loop: sample own 16 rows -> private sS slice -> MFMA
        #pragma unroll
        for (int kl = 0; kl < KPH; ++kl) {
            #pragma unroll
            for (int jp = 0; jp < 8; ++jp) {
                int prow = 16 * wv + 2 * jp + half;
                const int4   i0 = *(const int4*)&sIdx[kl][prow][0];
                const int4   i1 = *(const int4*)&sIdx[kl][prow][4];
                const float4 u0 = *(const float4*)&sCf[kl][prow][0];
                const float4 u1 = *(const float4*)&sCf[kl][prow][4];
                unsigned v0 = *(const unsigned*)(xbl + i0.x);
                unsigned v1 = *(const unsigned*)(xbl + i0.y);
                unsigned v2 = *(const unsigned*)(xbl + i0.z);
                unsigned v3 = *(const unsigned*)(xbl + i0.w);
                unsigned v4 = *(const unsigned*)(xbl + i1.x);
                unsigned v5 = *(const unsigned*)(xbl + i1.y);
                unsigned v6 = *(const unsigned*)(xbl + i1.z);
                unsigned v7 = *(const unsigned*)(xbl + i1.w);
                f32x2 s = {0.0f, 0.0f};
                s += up2(v0) * u0.x;
                s += up2(v1) * u0.y;
                s += up2(v2) * u0.z;
                s += up2(v3) * u0.w;
                s += up2(v4) * u1.x;
                s += up2(v5) * u1.y;
                s += up2(v6) * u1.z;
                s += up2(v7) * u1.w;
                unsigned pkv;
                asm("v_cvt_pk_bf16_f32 %0, %1, %2" : "=v"(pkv) : "v"(s.x), "v"(s.y));
                *(unsigned*)&sS[prow * LDW + 2 * c2] = pkv;
            }

            // ---- MFMA: wave's 16 positions x all 64 COUT, Kdim=64
            {
                const unsigned short* sWk = &sW[kl * (COUTC * LDW)];
                s16x8 b0 = *(const s16x8*)&sS[(16 * wv + n0) * LDW +      8 * q];
                s16x8 b1 = *(const s16x8*)&sS[(16 * wv + n0) * LDW + 32 + 8 * q];
                __builtin_amdgcn_s_setprio(1);
                #pragma unroll
                for (int g = 0; g < 4; ++g) {
                    s16x8 a0 = *(const s16x8*)&sWk[(16 * g + n0) * LDW +      8 * q];
                    s16x8 a1 = *(const s16x8*)&sWk[(16 * g + n0) * LDW + 32 + 8 * q];
                    acc[g] = __builtin_amdgcn_mfma_f32_16x16x32_bf16(a0, b0, acc[g], 0, 0, 0);
                    acc[g] = __builtin_amdgcn_mfma_f32_16x16x32_bf16(a1, b1, acc[g], 0, 0, 0);
                }
                __builtin_amdgcn_s_setprio(0);
            }
        }
    }

    // ---- epilogue: atomic partial accumulate; bias added by kg==0.
    const int p = p0 + 16 * wv + n0;
    #pragma unroll
    for (int g = 0; g < 4; ++g) {
        #pragma unroll
        for (int r = 0; r < 4; ++r) {
            int o = 16 * g + 4 * q + r;
            float v = acc[g][r];
            if (kg == 0) v += bias[o];
            unsafeAtomicAdd(&out[(size_t)(b * COUTC + o) * PP + p], v);
        }
    }
}

extern "C" void kernel_launch(void* const* d_in, const int* in_sizes, int n_in,
                              void* d_out, int out_size, void* d_ws, size_t ws_size,
                              hipStream_t stream) {
    const float* x    = (const float*)d_in[0];
    const float* off  = (const float*)d_in[1];
    const float* w    = (const float*)d_in[2];
    const float* bias = (const float*)d_in[3];
    float* out        = (float*)d_out;

    unsigned short* xt = (unsigned short*)d_ws;                       // 2*8192*64*2 = 2 MB
    unsigned short* wt = (unsigned short*)((char*)d_ws + (size_t)BB * PP * 64 * 2); // 221184 B

    hipLaunchKernelGGL(pre_kernel, dim3(256 + WBLOCKS + ZBLOCKS), dim3(256), 0,
                       stream, x, w, xt, wt, out);
    hipLaunchKernelGGL(deform_kernel, dim3(BB * (PP / TP), KGRP), dim3(256), 0, stream,
                       xt, off, wt, bias, out);
}

// Round 2
// 93.742 us; speedup vs baseline: 1.1023x; 1.0715x over previous
//
#include <hip/hip_runtime.h>
#include <hip/hip_bf16.h>

// Deformable 3D conv: B=2, CIN=COUT=64, D=8,H=32,W=32, K=27, stride=1,pad=1,dil=1
// Round 6 = round 5 + gather recut:
//  - 8-lane-group sampling: lane = (position lane>>3, channel-octet lane&7);
//    each corner = global_load_dwordx4 (16B/lane, 8 lanes = one 128B line),
//    one wave instruction covers 8 positions x 1 corner (8 lines, 1KB).
//    Gather instrs/kl: 64 -> 16; coord ds_reads: 32 -> 8.
//  - sIdx holds BYTE offsets; loads are uniform-base + 32-bit voffset (saddr
//    form) -> 1 v_add per corner instead of 64-bit pointer chains.
//  - everything else (wave-private sS, barrier-free kl loop, setprio, atomics)
//    unchanged from round 5.

#define BB    2
#define CINC  64
#define COUTC 64
#define DDEP  8
#define HGT   32
#define WID   32
#define KK    27
#define KGRP  3
#define KPG   9         // k's per blockIdx.y group
#define KPH   3         // k's per phase (weight-stage batch)
#define PP    8192      // DOUT*HOUT*WOUT
#define TP    64        // output positions per workgroup
#define LDW   72        // padded LDS row stride (bf16 elems)

typedef short s16x8 __attribute__((ext_vector_type(8)));
typedef float f32x4 __attribute__((ext_vector_type(4)));
typedef float f32x2 __attribute__((ext_vector_type(2)));
typedef unsigned int u32x4 __attribute__((ext_vector_type(4)));

__device__ __forceinline__ unsigned short f2bf(float f) {
    unsigned u = __builtin_bit_cast(unsigned, f);
    u += 0x7FFFu + ((u >> 16) & 1u);   // RNE
    return (unsigned short)(u >> 16);
}

__device__ __forceinline__ unsigned pack2bf(float lo, float hi) {
    return (unsigned)f2bf(lo) | ((unsigned)f2bf(hi) << 16);
}

// unpack 2 packed bf16 (2 channels) to float2
__device__ __forceinline__ f32x2 up2(unsigned v) {
    f32x2 r;
    r.x = __builtin_bit_cast(float, v << 16);
    r.y = __builtin_bit_cast(float, v & 0xFFFF0000u);
    return r;
}

// accumulate one corner: 16B (8 channels) * scalar weight into 4 f32x2 accums
__device__ __forceinline__ void acc8(const char* __restrict__ xc, unsigned off, float u,
                                     f32x2& s0, f32x2& s1, f32x2& s2, f32x2& s3) {
    u32x4 v = *(const u32x4*)(xc + off);
    f32x2 uu = {u, u};
    s0 += up2(v.x) * uu;
    s1 += up2(v.y) * uu;
    s2 += up2(v.z) * uu;
    s3 += up2(v.w) * uu;
}

// Fused pre-kernel:
//  blocks [0,256): transpose+convert x[b][c][s] fp32 -> xt[b][s][c] bf16
//  blocks [256,688): weight (COUT,CIN,27) fp32 -> wt[(k*64+o)*64+c] bf16
//  blocks [688,1712): zero-init out (replaces hipMemsetAsync dispatch)
#define WBLOCKS 432   // KK*COUTC*CINC / 256
#define ZBLOCKS 1024  // BB*COUTC*PP / 4 / 256
__global__ void pre_kernel(const float* __restrict__ x, const float* __restrict__ w,
                           unsigned short* __restrict__ xt, unsigned short* __restrict__ wt,
                           float* __restrict__ out) {
    __shared__ float sT[64][65];
    const int t    = threadIdx.x;
    const int lane = t & 63;
    const int wv   = t >> 6;
    const int half = lane >> 5;
    const int c2   = lane & 31;
    int blk = blockIdx.x;
    if (blk < 256) {
        int b  = blk >> 7;
        int s0 = (blk & 127) * 64;
        #pragma unroll
        for (int i = 0; i < 16; ++i) {
            int c = wv * 16 + i;
            sT[c][lane] = x[(size_t)(b * CINC + c) * PP + s0 + lane];
        }
        __syncthreads();
        #pragma unroll
        for (int i = 0; i < 8; ++i) {
            int s = wv * 16 + 2 * i + half;
            unsigned pk = pack2bf(sT[2 * c2][s], sT[2 * c2 + 1][s]);
            *(unsigned*)&xt[(size_t)(b * PP + s0 + s) * 64 + 2 * c2] = pk;
        }
    } else if (blk < 256 + WBLOCKS) {
        int id = (blk - 256) * 256 + t;
        if (id < KK * COUTC * CINC) {
            int c = id & 63;
            int o = (id >> 6) & 63;
            int k = id >> 12;
            wt[id] = f2bf(w[(o * CINC + c) * KK + k]);
        }
    } else {
        int id = (blk - 256 - WBLOCKS) * 256 + t;   // float4 index
        ((float4*)out)[id] = make_float4(0.f, 0.f, 0.f, 0.f);
    }
}

__global__ __launch_bounds__(256, 3) void deform_kernel(
    const unsigned short* __restrict__ xt, const float* __restrict__ off,
    const unsigned short* __restrict__ wt, const float* __restrict__ bias,
    float* __restrict__ out)
{
    __shared__ unsigned short sW[KPH * COUTC * LDW] __attribute__((aligned(16))); // 3x [o][c]
    __shared__ unsigned short sS[TP * LDW]          __attribute__((aligned(16))); // [p][c] wave-private slices
    __shared__ int   sIdx[KPH][TP][8] __attribute__((aligned(16)));  // corner BYTE offsets
    __shared__ float sCf[KPH][TP][8]  __attribute__((aligned(16)));  // corner weights

    const int t     = threadIdx.x;
    const int lane  = t & 63;
    const int wv    = t >> 6;
    const int choct = lane & 7;          // channel octet (8 channels)
    const int g8    = lane >> 3;         // position within iteration (0..7)
    const int ch16  = 16 * choct;        // byte offset of channel octet
    const int b     = blockIdx.x >> 7;
    const int p0    = (blockIdx.x & 127) * TP;
    const int kg    = blockIdx.y;

    const char* __restrict__ xc = (const char*)xt + (size_t)b * PP * 128;

    f32x4 acc[4];
    #pragma unroll
    for (int g = 0; g < 4; ++g) acc[g] = (f32x4)0.0f;

    const int n0  = lane & 15;
    const int q   = lane >> 4;
    const int cr  = lane & 15;   // coord row within wave slice
    const int ckl = lane >> 4;   // coord kl (0..3, 3 idle)

    #pragma unroll 1
    for (int ph = 0; ph < 3; ++ph) {
        const int kbase = kg * KPG + ph * KPH;

        __syncthreads();   // all waves done reading sW/sIdx of previous phase

        // ---- stage 3 weight tiles (coalesced 16B loads)
        const unsigned short* wk = wt + kbase * (COUTC * CINC);
        #pragma unroll
        for (int j = 0; j < 6; ++j) {
            int idx = j * 2048 + t * 8;
            int kl  = idx >> 12;
            int rem = idx & 4095;
            *(s16x8*)&sW[kl * (COUTC * LDW) + (rem >> 6) * LDW + (rem & 63)] =
                *(const s16x8*)(wk + idx);
        }

        // ---- coords: each wave computes its OWN 16 rows x 3 kl (48 lanes)
        if (ckl < KPH) {
            int k  = kbase + ckl;
            int pl = 16 * wv + cr;
            int pp = p0 + pl;
            int ow = pp & 31;
            int oh = (pp >> 5) & 31;
            int od = pp >> 10;
            int kd = k / 9;
            int kh = (k - kd * 9) / 3;
            int kw = k - kd * 9 - kh * 3;
            const float* ob = off + (size_t)(b * (3 * KK) + 3 * k) * PP + pp;
            float zd = (float)(od - 1 + kd) + ob[0];
            float zh = (float)(oh - 1 + kh) + ob[PP];
            float zw = (float)(ow - 1 + kw) + ob[2 * PP];

            float fdf = floorf(zd); int d0 = (int)fdf; float fd = zd - fdf;
            float fhf = floorf(zh); int h0 = (int)fhf; float fh = zh - fhf;
            float fwf = floorf(zw); int w0 = (int)fwf; float fw = zw - fwf;

            float Bd0 = (d0 >= 0     && d0 < DDEP)     ? 1.0f - fd : 0.0f;
            float Bd1 = (d0 + 1 >= 0 && d0 + 1 < DDEP) ? fd        : 0.0f;
            float Ch0 = (h0 >= 0     && h0 < HGT)      ? 1.0f - fh : 0.0f;
            float Ch1 = (h0 + 1 >= 0 && h0 + 1 < HGT)  ? fh        : 0.0f;
            float Aw0 = (w0 >= 0     && w0 < WID)      ? 1.0f - fw : 0.0f;
            float Aw1 = (w0 + 1 >= 0 && w0 + 1 < WID)  ? fw        : 0.0f;
            int dc0 = min(max(d0, 0), DDEP - 1);
            int dc1 = min(max(d0 + 1, 0), DDEP - 1);
            int hc0 = min(max(h0, 0), HGT - 1);
            int hc1 = min(max(h0 + 1, 0), HGT - 1);
            int wc0 = min(max(w0, 0), WID - 1);
            int wc1 = min(max(w0 + 1, 0), WID - 1);

            // BYTE offsets: one (d,h,w) line = 64 ch * 2B = 128B
            int dhb0 = (dc0 * HGT + hc0) * (WID * 128);
            int dhb1 = (dc0 * HGT + hc1) * (WID * 128);
            int dhb2 = (dc1 * HGT + hc0) * (WID * 128);
            int dhb3 = (dc1 * HGT + hc1) * (WID * 128);
            int wo0 = wc0 * 128, wo1 = wc1 * 128;
            sIdx[ckl][pl][0] = dhb0 + wo0;
            sIdx[ckl][pl][1] = dhb1 + wo0;
            sIdx[ckl][pl][2] = dhb2 + wo0;
            sIdx[ckl][pl][3] = dhb3 + wo0;
            sIdx[ckl][pl][4] = dhb0 + wo1;
            sIdx[ckl][pl][5] = dhb1 + wo1;
            sIdx[ckl][pl][6] = dhb2 + wo1;
            sIdx[ckl][pl][7] = dhb3 + wo1;
            float bc0 = Bd0 * Ch0, bc1 = Bd0 * Ch1, bc2 = Bd1 * Ch0, bc3 = Bd1 * Ch1;
            sCf[ckl][pl][0] = bc0 * Aw0;
            sCf[ckl][pl][1] = bc1 * Aw0;
            sCf[ckl][pl][2] = bc2 * Aw0;
            sCf[ckl][pl][3] = bc3 * Aw0;
            sCf[ckl][pl][4] = bc0 * Aw1;
            sCf[ckl][pl][5] = bc1 * Aw1;
            sCf[ckl][pl][6] = bc2 * Aw1;
            sCf[ckl][pl][7] = bc3 * Aw1;
        }
        __syncthreads();   // sW (and coords) visible

        // ---- barrier-free kl loop: sample own 16 rows -> private sS slice -> MFMA
        #pragma unroll
        for (int kl = 0; kl < KPH; ++kl) {
            #pragma unroll
            for (int it = 0; it < 2; ++it) {
                int prow = 16 * wv + 8 * it + g8;
                const int4   i0 = *(const int4*)&sIdx[kl][prow][0];
                const int4   i1 = *(const int4*)&sIdx[kl][prow][4];
                const float4 u0 = *(const float4*)&sCf[kl][prow][0];
                const float4 u1 = *(const float4*)&sCf[kl][prow][4];
                f32x2 s0 = {0.f, 0.f}, s1 = {0.f, 0.f}, s2 = {0.f, 0.f}, s3 = {0.f, 0.f};
                acc8(xc, (unsigned)(i0.x + ch16), u0.x, s0, s1, s2, s3);
                acc8(xc, (unsigned)(i0.y + ch16), u0.y, s0, s1, s2, s3);
                acc8(xc, (unsigned)(i0.z + ch16), u0.z, s0, s1, s2, s3);
                acc8(xc, (unsigned)(i0.w + ch16), u0.w, s0, s1, s2, s3);
                acc8(xc, (unsigned)(i1.x + ch16), u1.x, s0, s1, s2, s3);
                acc8(xc, (unsigned)(i1.y + ch16), u1.y, s0, s1, s2, s3);
                acc8(xc, (unsigned)(i1.z + ch16), u1.z, s0, s1, s2, s3);
                acc8(xc, (unsigned)(i1.w + ch16), u1.w, s0, s1, s2, s3);
                unsigned pk0, pk1, pk2, pk3;
                asm("v_cvt_pk_bf16_f32 %0, %1, %2" : "=v"(pk0) : "v"(s0.x), "v"(s0.y));
                asm("v_cvt_pk_bf16_f32 %0, %1, %2" : "=v"(pk1) : "v"(s1.x), "v"(s1.y));
                asm("v_cvt_pk_bf16_f32 %0, %1, %2" : "=v"(pk2) : "v"(s2.x), "v"(s2.y));
                asm("v_cvt_pk_bf16_f32 %0, %1, %2" : "=v"(pk3) : "v"(s3.x), "v"(s3.y));
                u32x4 pk = {pk0, pk1, pk2, pk3};
                *(u32x4*)&sS[prow * LDW + 8 * choct] = pk;
            }

            // ---- MFMA: wave's 16 positions x all 64 COUT, Kdim=64
            {
                const unsigned short* sWk = &sW[kl * (COUTC * LDW)];
                s16x8 b0 = *(const s16x8*)&sS[(16 * wv + n0) * LDW +      8 * q];
                s16x8 b1 = *(const s16x8*)&sS[(16 * wv + n0) * LDW + 32 + 8 * q];
                __builtin_amdgcn_s_setprio(1);
                #pragma unroll
                for (int g = 0; g < 4; ++g) {
                    s16x8 a0 = *(const s16x8*)&sWk[(16 * g + n0) * LDW +      8 * q];
                    s16x8 a1 = *(const s16x8*)&sWk[(16 * g + n0) * LDW + 32 + 8 * q];
                    acc[g] = __builtin_amdgcn_mfma_f32_16x16x32_bf16(a0, b0, acc[g], 0, 0, 0);
                    acc[g] = __builtin_amdgcn_mfma_f32_16x16x32_bf16(a1, b1, acc[g], 0, 0, 0);
                }
                __builtin_amdgcn_s_setprio(0);
            }
        }
    }

    // ---- epilogue: atomic partial accumulate; bias added by kg==0.
    const int p = p0 + 16 * wv + n0;
    #pragma unroll
    for (int g = 0; g < 4; ++g) {
        #pragma unroll
        for (int r = 0; r < 4; ++r) {
            int o = 16 * g + 4 * q + r;
            float v = acc[g][r];
            if (kg == 0) v += bias[o];
            unsafeAtomicAdd(&out[(size_t)(b * COUTC + o) * PP + p], v);
        }
    }
}

extern "C" void kernel_launch(void* const* d_in, const int* in_sizes, int n_in,
                              void* d_out, int out_size, void* d_ws, size_t ws_size,
                              hipStream_t stream) {
    const float* x    = (const float*)d_in[0];
    const float* off  = (const float*)d_in[1];
    const float* w    = (const float*)d_in[2];
    const float* bias = (const float*)d_in[3];
    float* out        = (float*)d_out;

    unsigned short* xt = (unsigned short*)d_ws;                       // 2*8192*64*2 = 2 MB
    unsigned short* wt = (unsigned short*)((char*)d_ws + (size_t)BB * PP * 64 * 2); // 221184 B

    hipLaunchKernelGGL(pre_kernel, dim3(256 + WBLOCKS + ZBLOCKS), dim3(256), 0,
                       stream, x, w, xt, wt, out);
    hipLaunchKernelGGL(deform_kernel, dim3(BB * (PP / TP), KGRP), dim3(256), 0, stream,
                       xt, off, wt, bias, out);
}

// Round 3
// 92.251 us; speedup vs baseline: 1.1201x; 1.0162x over previous
//
#include <hip/hip_runtime.h>
#include <hip/hip_fp16.h>

// Deformable 3D conv: B=2, CIN=COUT=64, D=8,H=32,W=32, K=27, stride=1,pad=1,dil=1
// Round 7 = round 6 with the sampled-data path recut from bf16 to fp16:
//  - v_pk_fma_f16 does 2 channels/inst with NO unpack (bf16 needed shift+and+pk_fma)
//    -> sampling VALU per 8-corner iter: ~104 -> ~40
//  - accumulators are packed half2; stored to sS directly (cvt_pk packs deleted)
//  - corner weights pre-packed to broadcast half2 at coord time
//  - MFMA: mfma_f32_16x16x32_f16 (same rate as bf16); fp16 also IMPROVES precision
//    (10-bit vs 7-bit mantissa)
//  - structure (wave-private sS, barrier-free kl loop, KGRP=3, atomics) unchanged

#define BB    2
#define CINC  64
#define COUTC 64
#define DDEP  8
#define HGT   32
#define WID   32
#define KK    27
#define KGRP  3
#define KPG   9         // k's per blockIdx.y group
#define KPH   3         // k's per phase (weight-stage batch)
#define PP    8192      // DOUT*HOUT*WOUT
#define TP    64        // output positions per workgroup
#define LDW   72        // padded LDS row stride (fp16 elems)

typedef _Float16 f16x8 __attribute__((ext_vector_type(8)));
typedef float f32x4 __attribute__((ext_vector_type(4)));
typedef unsigned int u32x4 __attribute__((ext_vector_type(4)));

__device__ __forceinline__ __half2 h2(unsigned v) { return __builtin_bit_cast(__half2, v); }
__device__ __forceinline__ unsigned h2u(__half2 h) { return __builtin_bit_cast(unsigned, h); }

// accumulate one corner: 16B (8 channels as 4 half2) * broadcast half2 weight
__device__ __forceinline__ void acc8h(const char* __restrict__ xc, unsigned off, __half2 uu,
                                      __half2& s0, __half2& s1, __half2& s2, __half2& s3) {
    u32x4 v = *(const u32x4*)(xc + off);
    s0 = __hfma2(h2(v.x), uu, s0);
    s1 = __hfma2(h2(v.y), uu, s1);
    s2 = __hfma2(h2(v.z), uu, s2);
    s3 = __hfma2(h2(v.w), uu, s3);
}

// Fused pre-kernel:
//  blocks [0,256): transpose+convert x[b][c][s] fp32 -> xt[b][s][c] fp16
//  blocks [256,688): weight (COUT,CIN,27) fp32 -> wt[(k*64+o)*64+c] fp16
//  blocks [688,1712): zero-init out (replaces hipMemsetAsync dispatch)
#define WBLOCKS 432   // KK*COUTC*CINC / 256
#define ZBLOCKS 1024  // BB*COUTC*PP / 4 / 256
__global__ void pre_kernel(const float* __restrict__ x, const float* __restrict__ w,
                           unsigned short* __restrict__ xt, unsigned short* __restrict__ wt,
                           float* __restrict__ out) {
    __shared__ float sT[64][65];
    const int t    = threadIdx.x;
    const int lane = t & 63;
    const int wv   = t >> 6;
    const int half = lane >> 5;
    const int c2   = lane & 31;
    int blk = blockIdx.x;
    if (blk < 256) {
        int b  = blk >> 7;
        int s0 = (blk & 127) * 64;
        #pragma unroll
        for (int i = 0; i < 16; ++i) {
            int c = wv * 16 + i;
            sT[c][lane] = x[(size_t)(b * CINC + c) * PP + s0 + lane];
        }
        __syncthreads();
        #pragma unroll
        for (int i = 0; i < 8; ++i) {
            int s = wv * 16 + 2 * i + half;
            unsigned pk = h2u(__floats2half2_rn(sT[2 * c2][s], sT[2 * c2 + 1][s]));
            *(unsigned*)&xt[(size_t)(b * PP + s0 + s) * 64 + 2 * c2] = pk;
        }
    } else if (blk < 256 + WBLOCKS) {
        int id = (blk - 256) * 256 + t;
        if (id < KK * COUTC * CINC) {
            int c = id & 63;
            int o = (id >> 6) & 63;
            int k = id >> 12;
            __half hw = __float2half(w[(o * CINC + c) * KK + k]);
            wt[id] = __builtin_bit_cast(unsigned short, hw);
        }
    } else {
        int id = (blk - 256 - WBLOCKS) * 256 + t;   // float4 index
        ((float4*)out)[id] = make_float4(0.f, 0.f, 0.f, 0.f);
    }
}

__global__ __launch_bounds__(256, 3) void deform_kernel(
    const unsigned short* __restrict__ xt, const float* __restrict__ off,
    const unsigned short* __restrict__ wt, const float* __restrict__ bias,
    float* __restrict__ out)
{
    __shared__ unsigned short sW[KPH * COUTC * LDW] __attribute__((aligned(16))); // 3x [o][c]
    __shared__ unsigned short sS[TP * LDW]          __attribute__((aligned(16))); // [p][c] wave-private slices
    __shared__ int      sIdx[KPH][TP][8] __attribute__((aligned(16)));  // corner BYTE offsets
    __shared__ unsigned sCfh[KPH][TP][8] __attribute__((aligned(16)));  // corner weights (bcast half2)

    const int t     = threadIdx.x;
    const int lane  = t & 63;
    const int wv    = t >> 6;
    const int choct = lane & 7;          // channel octet (8 channels)
    const int g8    = lane >> 3;         // position within iteration (0..7)
    const int ch16  = 16 * choct;        // byte offset of channel octet
    const int b     = blockIdx.x >> 7;
    const int p0    = (blockIdx.x & 127) * TP;
    const int kg    = blockIdx.y;

    const char* __restrict__ xc = (const char*)xt + (size_t)b * PP * 128;

    f32x4 acc[4];
    #pragma unroll
    for (int g = 0; g < 4; ++g) acc[g] = (f32x4)0.0f;

    const int n0  = lane & 15;
    const int q   = lane >> 4;
    const int cr  = lane & 15;   // coord row within wave slice
    const int ckl = lane >> 4;   // coord kl (0..3, 3 idle)

    #pragma unroll 1
    for (int ph = 0; ph < 3; ++ph) {
        const int kbase = kg * KPG + ph * KPH;

        __syncthreads();   // all waves done reading sW/sIdx of previous phase

        // ---- stage 3 weight tiles (coalesced 16B loads)
        const unsigned short* wk = wt + kbase * (COUTC * CINC);
        #pragma unroll
        for (int j = 0; j < 6; ++j) {
            int idx = j * 2048 + t * 8;
            int kl  = idx >> 12;
            int rem = idx & 4095;
            *(f16x8*)&sW[kl * (COUTC * LDW) + (rem >> 6) * LDW + (rem & 63)] =
                *(const f16x8*)(wk + idx);
        }

        // ---- coords: each wave computes its OWN 16 rows x 3 kl (48 lanes)
        if (ckl < KPH) {
            int k  = kbase + ckl;
            int pl = 16 * wv + cr;
            int pp = p0 + pl;
            int ow = pp & 31;
            int oh = (pp >> 5) & 31;
            int od = pp >> 10;
            int kd = k / 9;
            int kh = (k - kd * 9) / 3;
            int kw = k - kd * 9 - kh * 3;
            const float* ob = off + (size_t)(b * (3 * KK) + 3 * k) * PP + pp;
            float zd = (float)(od - 1 + kd) + ob[0];
            float zh = (float)(oh - 1 + kh) + ob[PP];
            float zw = (float)(ow - 1 + kw) + ob[2 * PP];

            float fdf = floorf(zd); int d0 = (int)fdf; float fd = zd - fdf;
            float fhf = floorf(zh); int h0 = (int)fhf; float fh = zh - fhf;
            float fwf = floorf(zw); int w0 = (int)fwf; float fw = zw - fwf;

            float Bd0 = (d0 >= 0     && d0 < DDEP)     ? 1.0f - fd : 0.0f;
            float Bd1 = (d0 + 1 >= 0 && d0 + 1 < DDEP) ? fd        : 0.0f;
            float Ch0 = (h0 >= 0     && h0 < HGT)      ? 1.0f - fh : 0.0f;
            float Ch1 = (h0 + 1 >= 0 && h0 + 1 < HGT)  ? fh        : 0.0f;
            float Aw0 = (w0 >= 0     && w0 < WID)      ? 1.0f - fw : 0.0f;
            float Aw1 = (w0 + 1 >= 0 && w0 + 1 < WID)  ? fw        : 0.0f;
            int dc0 = min(max(d0, 0), DDEP - 1);
            int dc1 = min(max(d0 + 1, 0), DDEP - 1);
            int hc0 = min(max(h0, 0), HGT - 1);
            int hc1 = min(max(h0 + 1, 0), HGT - 1);
            int wc0 = min(max(w0, 0), WID - 1);
            int wc1 = min(max(w0 + 1, 0), WID - 1);

            // BYTE offsets: one (d,h,w) line = 64 ch * 2B = 128B
            int dhb0 = (dc0 * HGT + hc0) * (WID * 128);
            int dhb1 = (dc0 * HGT + hc1) * (WID * 128);
            int dhb2 = (dc1 * HGT + hc0) * (WID * 128);
            int dhb3 = (dc1 * HGT + hc1) * (WID * 128);
            int wo0 = wc0 * 128, wo1 = wc1 * 128;
            sIdx[ckl][pl][0] = dhb0 + wo0;
            sIdx[ckl][pl][1] = dhb1 + wo0;
            sIdx[ckl][pl][2] = dhb2 + wo0;
            sIdx[ckl][pl][3] = dhb3 + wo0;
            sIdx[ckl][pl][4] = dhb0 + wo1;
            sIdx[ckl][pl][5] = dhb1 + wo1;
            sIdx[ckl][pl][6] = dhb2 + wo1;
            sIdx[ckl][pl][7] = dhb3 + wo1;
            float bc0 = Bd0 * Ch0, bc1 = Bd0 * Ch1, bc2 = Bd1 * Ch0, bc3 = Bd1 * Ch1;
            float u0 = bc0 * Aw0, u1 = bc1 * Aw0, u2 = bc2 * Aw0, u3 = bc3 * Aw0;
            float u4 = bc0 * Aw1, u5 = bc1 * Aw1, u6 = bc2 * Aw1, u7 = bc3 * Aw1;
            sCfh[ckl][pl][0] = h2u(__half2half2(__float2half(u0)));
            sCfh[ckl][pl][1] = h2u(__half2half2(__float2half(u1)));
            sCfh[ckl][pl][2] = h2u(__half2half2(__float2half(u2)));
            sCfh[ckl][pl][3] = h2u(__half2half2(__float2half(u3)));
            sCfh[ckl][pl][4] = h2u(__half2half2(__float2half(u4)));
            sCfh[ckl][pl][5] = h2u(__half2half2(__float2half(u5)));
            sCfh[ckl][pl][6] = h2u(__half2half2(__float2half(u6)));
            sCfh[ckl][pl][7] = h2u(__half2half2(__float2half(u7)));
        }
        __syncthreads();   // sW (and coords) visible

        // ---- barrier-free kl loop: sample own 16 rows -> private sS slice -> MFMA
        #pragma unroll
        for (int kl = 0; kl < KPH; ++kl) {
            #pragma unroll
            for (int it = 0; it < 2; ++it) {
                int prow = 16 * wv + 8 * it + g8;
                const int4 i0 = *(const int4*)&sIdx[kl][prow][0];
                const int4 i1 = *(const int4*)&sIdx[kl][prow][4];
                const u32x4 c0 = *(const u32x4*)&sCfh[kl][prow][0];
                const u32x4 c1 = *(const u32x4*)&sCfh[kl][prow][4];
                __half2 s0 = h2(0u), s1 = h2(0u), s2 = h2(0u), s3 = h2(0u);
                acc8h(xc, (unsigned)(i0.x + ch16), h2(c0.x), s0, s1, s2, s3);
                acc8h(xc, (unsigned)(i0.y + ch16), h2(c0.y), s0, s1, s2, s3);
                acc8h(xc, (unsigned)(i0.z + ch16), h2(c0.z), s0, s1, s2, s3);
                acc8h(xc, (unsigned)(i0.w + ch16), h2(c0.w), s0, s1, s2, s3);
                acc8h(xc, (unsigned)(i1.x + ch16), h2(c1.x), s0, s1, s2, s3);
                acc8h(xc, (unsigned)(i1.y + ch16), h2(c1.y), s0, s1, s2, s3);
                acc8h(xc, (unsigned)(i1.z + ch16), h2(c1.z), s0, s1, s2, s3);
                acc8h(xc, (unsigned)(i1.w + ch16), h2(c1.w), s0, s1, s2, s3);
                u32x4 pk = {h2u(s0), h2u(s1), h2u(s2), h2u(s3)};
                *(u32x4*)&sS[prow * LDW + 8 * choct] = pk;
            }

            // ---- MFMA: wave's 16 positions x all 64 COUT, Kdim=64
            {
                const unsigned short* sWk = &sW[kl * (COUTC * LDW)];
                f16x8 b0 = *(const f16x8*)&sS[(16 * wv + n0) * LDW +      8 * q];
                f16x8 b1 = *(const f16x8*)&sS[(16 * wv + n0) * LDW + 32 + 8 * q];
                __builtin_amdgcn_s_setprio(1);
                #pragma unroll
                for (int g = 0; g < 4; ++g) {
                    f16x8 a0 = *(const f16x8*)&sWk[(16 * g + n0) * LDW +      8 * q];
                    f16x8 a1 = *(const f16x8*)&sWk[(16 * g + n0) * LDW + 32 + 8 * q];
                    acc[g] = __builtin_amdgcn_mfma_f32_16x16x32_f16(a0, b0, acc[g], 0, 0, 0);
                    acc[g] = __builtin_amdgcn_mfma_f32_16x16x32_f16(a1, b1, acc[g], 0, 0, 0);
                }
                __builtin_amdgcn_s_setprio(0);
            }
        }
    }

    // ---- epilogue: atomic partial accumulate; bias added by kg==0.
    const int p = p0 + 16 * wv + n0;
    #pragma unroll
    for (int g = 0; g < 4; ++g) {
        #pragma unroll
        for (int r = 0; r < 4; ++r) {
            int o = 16 * g + 4 * q + r;
            float v = acc[g][r];
            if (kg == 0) v += bias[o];
            unsafeAtomicAdd(&out[(size_t)(b * COUTC + o) * PP + p], v);
        }
    }
}

extern "C" void kernel_launch(void* const* d_in, const int* in_sizes, int n_in,
                              void* d_out, int out_size, void* d_ws, size_t ws_size,
                              hipStream_t stream) {
    const float* x    = (const float*)d_in[0];
    const float* off  = (const float*)d_in[1];
    const float* w    = (const float*)d_in[2];
    const float* bias = (const float*)d_in[3];
    float* out        = (float*)d_out;

    unsigned short* xt = (unsigned short*)d_ws;                       // 2*8192*64*2 = 2 MB
    unsigned short* wt = (unsigned short*)((char*)d_ws + (size_t)BB * PP * 64 * 2); // 221184 B

    hipLaunchKernelGGL(pre_kernel, dim3(256 + WBLOCKS + ZBLOCKS), dim3(256), 0,
                       stream, x, w, xt, wt, out);
    hipLaunchKernelGGL(deform_kernel, dim3(BB * (PP / TP), KGRP), dim3(256), 0, stream,
                       xt, off, wt, bias, out);
}